// Round 3
// baseline (3283.165 us; speedup 1.0000x reference)
//
#include <hip/hip_runtime.h>

#define TLEN  1024
#define HID   96
#define NGATE 384
#define NTHR  768
#define WSTR  12   // floats per thread kept in LDS (cols 84..95 of the phase-C row)

__device__ __forceinline__ float sigf(float x) {
    return 1.0f / (1.0f + __expf(-x));
}
__device__ __forceinline__ float tanh_fast(float x) {
    float e = __expf(2.0f * x);
    return 1.0f - 2.0f / (e + 1.0f);
}

// FMA a float4 of weights against a float4 of h (broadcast from LDS)
#define QFMA(W, HV, I)                                   \
    {                                                    \
        float4 h4 = (HV)[I];                             \
        acc.x = fmaf((W).x, h4.x, acc.x);                \
        acc.y = fmaf((W).y, h4.y, acc.y);                \
        acc.z = fmaf((W).z, h4.z, acc.z);                \
        acc.w = fmaf((W).w, h4.w, acc.w);                \
    }

extern "C" __global__ void __launch_bounds__(NTHR)
__attribute__((amdgpu_waves_per_eu(3, 3)))
lstm2_fused(const float* __restrict__ x,
            const float* __restrict__ Wih0, const float* __restrict__ Whh0,
            const float* __restrict__ bih0, const float* __restrict__ bhh0,
            const float* __restrict__ Wih1, const float* __restrict__ Whh1,
            const float* __restrict__ bih1, const float* __restrict__ bhh1,
            const float* __restrict__ Wl,   const float* __restrict__ bl,
            float* __restrict__ out)
{
    __shared__ __attribute__((aligned(16))) float x_s[TLEN];
    __shared__ __attribute__((aligned(16))) float out_s[TLEN];
    __shared__ __attribute__((aligned(16))) float g_s[NGATE];
    __shared__ __attribute__((aligned(16))) float h1_s[HID];
    __shared__ __attribute__((aligned(16))) float h2_s[HID];
    __shared__ __attribute__((aligned(16))) float po_s[HID];
    __shared__ __attribute__((aligned(16))) float wlds[NTHR * WSTR];  // 36 KB

    const int tid  = threadIdx.x;
    const int b    = blockIdx.x;
    const int j    = tid >> 1;   // gate row 0..383 (torch order i,f,g,o)
    const int half = tid & 1;

    // stage this batch's x sequence (I=1 -> 4 KiB)
    for (int i = tid; i < TLEN; i += NTHR) x_s[i] = x[b * TLEN + i];

    // ---- phase-A weights: Whh0[j][48*half .. +47], 12 NAMED float4s ----
    const float4* p0 = reinterpret_cast<const float4*>(Whh0 + j * HID + 48 * half);
    float4 a0 = p0[0],  a1 = p0[1],  a2 = p0[2],  a3 = p0[3];
    float4 a4 = p0[4],  a5 = p0[5],  a6 = p0[6],  a7 = p0[7];
    float4 a8 = p0[8],  a9 = p0[9],  a10 = p0[10], a11 = p0[11];

    // ---- phase-C weights: row j of (half ? Whh1 : Wih1) ----
    // cols 0..83 in 21 NAMED float4s; cols 84..95 (3 float4s) go to LDS
    const float* m1 = half ? Whh1 : Wih1;
    const float4* p1 = reinterpret_cast<const float4*>(m1 + j * HID);
    float4 b0 = p1[0],  b1 = p1[1],  b2 = p1[2],  b3 = p1[3];
    float4 b4 = p1[4],  b5 = p1[5],  b6 = p1[6],  b7 = p1[7];
    float4 b8 = p1[8],  b9 = p1[9],  b10 = p1[10], b11 = p1[11];
    float4 b12 = p1[12], b13 = p1[13], b14 = p1[14], b15 = p1[15];
    float4 b16 = p1[16], b17 = p1[17], b18 = p1[18], b19 = p1[19];
    float4 b20 = p1[20];
    {
        float4* wl = reinterpret_cast<float4*>(wlds + tid * WSTR);
        wl[0] = p1[21]; wl[1] = p1[22]; wl[2] = p1[23];
    }

    const float bias0 = bih0[j] + bhh0[j];
    const float wx0   = Wih0[j];              // W_ih0 is [384,1]
    const float bias1 = bih1[j] + bhh1[j];
    const float wl_u  = (tid < HID) ? Wl[tid] : 0.0f;
    const float bl0   = bl[0];

    float c1 = 0.0f, c2 = 0.0f;
    if (tid < HID) { h1_s[tid] = 0.0f; h2_s[tid] = 0.0f; }
    __syncthreads();

    #pragma unroll 1
    for (int t = 0; t < TLEN; ++t) {
        // ---- A: g0[j] = bias0 + x_t*Wih0[j] + dot(Whh0[j], h1_prev) ----
        {
            const float4* hA = reinterpret_cast<const float4*>(h1_s + 48 * half);
            float4 acc = make_float4(0.f, 0.f, 0.f, 0.f);
            QFMA(a0, hA, 0)  QFMA(a1, hA, 1)  QFMA(a2, hA, 2)  QFMA(a3, hA, 3)
            QFMA(a4, hA, 4)  QFMA(a5, hA, 5)  QFMA(a6, hA, 6)  QFMA(a7, hA, 7)
            QFMA(a8, hA, 8)  QFMA(a9, hA, 9)  QFMA(a10, hA, 10) QFMA(a11, hA, 11)
            float s = (acc.x + acc.y) + (acc.z + acc.w);
            s += __shfl_xor(s, 1);
            if (half == 0) g_s[j] = s + bias0 + wx0 * x_s[t];
        }
        __syncthreads();
        // ---- B: layer-1 pointwise (96 units) ----
        if (tid < HID) {
            float gi = g_s[tid];
            float gf = g_s[HID + tid];
            float gg = g_s[2 * HID + tid];
            float go = g_s[3 * HID + tid];
            c1 = sigf(gf) * c1 + sigf(gi) * tanh_fast(gg);
            h1_s[tid] = sigf(go) * tanh_fast(c1);
        }
        __syncthreads();
        // ---- C: g1[j] = bias1 + dot(Wih1[j], h1_t) + dot(Whh1[j], h2_prev) ----
        {
            const float4* hC = reinterpret_cast<const float4*>(half ? h2_s : h1_s);
            float4 acc = make_float4(0.f, 0.f, 0.f, 0.f);
            QFMA(b0, hC, 0)   QFMA(b1, hC, 1)   QFMA(b2, hC, 2)   QFMA(b3, hC, 3)
            QFMA(b4, hC, 4)   QFMA(b5, hC, 5)   QFMA(b6, hC, 6)   QFMA(b7, hC, 7)
            QFMA(b8, hC, 8)   QFMA(b9, hC, 9)   QFMA(b10, hC, 10) QFMA(b11, hC, 11)
            QFMA(b12, hC, 12) QFMA(b13, hC, 13) QFMA(b14, hC, 14) QFMA(b15, hC, 15)
            QFMA(b16, hC, 16) QFMA(b17, hC, 17) QFMA(b18, hC, 18) QFMA(b19, hC, 19)
            QFMA(b20, hC, 20)
            // tail cols 84..95 from LDS; opaque zero keeps these reads inside the
            // loop (otherwise LICM hoists 12 loop-invariant floats back into VGPRs)
            int zr;
            asm volatile("v_mov_b32 %0, 0" : "=v"(zr));
            const float4* wl = reinterpret_cast<const float4*>(wlds + tid * WSTR + zr);
            {
                float4 w = wl[0];
                float4 h4 = hC[21];
                acc.x = fmaf(w.x, h4.x, acc.x); acc.y = fmaf(w.y, h4.y, acc.y);
                acc.z = fmaf(w.z, h4.z, acc.z); acc.w = fmaf(w.w, h4.w, acc.w);
            }
            {
                float4 w = wl[1];
                float4 h4 = hC[22];
                acc.x = fmaf(w.x, h4.x, acc.x); acc.y = fmaf(w.y, h4.y, acc.y);
                acc.z = fmaf(w.z, h4.z, acc.z); acc.w = fmaf(w.w, h4.w, acc.w);
            }
            {
                float4 w = wl[2];
                float4 h4 = hC[23];
                acc.x = fmaf(w.x, h4.x, acc.x); acc.y = fmaf(w.y, h4.y, acc.y);
                acc.z = fmaf(w.z, h4.z, acc.z); acc.w = fmaf(w.w, h4.w, acc.w);
            }
            float s = (acc.x + acc.y) + (acc.z + acc.w);
            s += __shfl_xor(s, 1);
            if (half == 0) g_s[j] = s + bias1;
        }
        __syncthreads();
        // ---- D: layer-2 pointwise + linear-head partials ----
        if (tid < HID) {
            float gi = g_s[tid];
            float gf = g_s[HID + tid];
            float gg = g_s[2 * HID + tid];
            float go = g_s[3 * HID + tid];
            c2 = sigf(gf) * c2 + sigf(gi) * tanh_fast(gg);
            float h2 = sigf(go) * tanh_fast(c2);
            h2_s[tid] = h2;
            po_s[tid] = wl_u * h2;
        }
        __syncthreads();
        // ---- E: out[b][t] = sum(po) + bl (wave 0; no trailing barrier needed) ----
        if (tid < 64) {
            float v = po_s[tid] + ((tid < 32) ? po_s[64 + tid] : 0.0f);
            v += __shfl_xor(v, 32);
            v += __shfl_xor(v, 16);
            v += __shfl_xor(v, 8);
            v += __shfl_xor(v, 4);
            v += __shfl_xor(v, 2);
            v += __shfl_xor(v, 1);
            if (tid == 0) out_s[t] = v + bl0;
        }
    }
    __syncthreads();
    for (int i = tid; i < TLEN; i += NTHR) out[b * TLEN + i] = out_s[i];
}

extern "C" void kernel_launch(void* const* d_in, const int* in_sizes, int n_in,
                              void* d_out, int out_size, void* d_ws, size_t ws_size,
                              hipStream_t stream)
{
    (void)in_sizes; (void)n_in; (void)d_ws; (void)ws_size; (void)out_size;
    const float* x    = (const float*)d_in[0];
    const float* Wih0 = (const float*)d_in[1];
    const float* Whh0 = (const float*)d_in[2];
    const float* bih0 = (const float*)d_in[3];
    const float* bhh0 = (const float*)d_in[4];
    const float* Wih1 = (const float*)d_in[5];
    const float* Whh1 = (const float*)d_in[6];
    const float* bih1 = (const float*)d_in[7];
    const float* bhh1 = (const float*)d_in[8];
    const float* Wl   = (const float*)d_in[9];
    const float* bl   = (const float*)d_in[10];

    lstm2_fused<<<dim3(256), dim3(NTHR), 0, stream>>>(
        x, Wih0, Whh0, bih0, bhh0, Wih1, Whh1, bih1, bhh1, Wl, bl,
        (float*)d_out);
}

// Round 4
// 2689.348 us; speedup vs baseline: 1.2208x; 1.2208x over previous
//
#include <hip/hip_runtime.h>

#define TLEN  1024
#define HID   96
#define NGATE 384
#define NTHR  768
#define WSTR  24   // floats per thread in LDS (phase-C cols 72..95)
#define WPAD  28   // row stride in floats: 112B, 16B-aligned, (7l+k)&7 bank-perm

__device__ __forceinline__ float sigf(float x) {
    return 1.0f / (1.0f + __expf(-x));
}
__device__ __forceinline__ float tanh_fast(float x) {
    float e = __expf(2.0f * x);
    return 1.0f - 2.0f / (e + 1.0f);
}

// FMA a float4 of weights against a float4 of h (broadcast from LDS)
#define QFMA(W, HV, I)                                   \
    {                                                    \
        float4 h4 = (HV)[I];                             \
        acc.x = fmaf((W).x, h4.x, acc.x);                \
        acc.y = fmaf((W).y, h4.y, acc.y);                \
        acc.z = fmaf((W).z, h4.z, acc.z);                \
        acc.w = fmaf((W).w, h4.w, acc.w);                \
    }

extern "C" __global__ void __launch_bounds__(NTHR)
__attribute__((amdgpu_waves_per_eu(3, 3)))
lstm2_fused(const float* __restrict__ x,
            const float* __restrict__ Wih0, const float* __restrict__ Whh0,
            const float* __restrict__ bih0, const float* __restrict__ bhh0,
            const float* __restrict__ Wih1, const float* __restrict__ Whh1,
            const float* __restrict__ bih1, const float* __restrict__ bhh1,
            const float* __restrict__ Wl,   const float* __restrict__ bl,
            float* __restrict__ out)
{
    // ~94.6 KB total LDS -> only ONE 768-thread block fits per CU. This is
    // deliberate: it caps computeOccupancy() at 3 waves/EU so the scheduler's
    // VGPR budget is 168 and it stops spilling weights to chase phantom waves.
    __shared__ __attribute__((aligned(16))) float x_s[TLEN];
    __shared__ __attribute__((aligned(16))) float out_s[TLEN];
    __shared__ __attribute__((aligned(16))) float g_s[NGATE];
    __shared__ __attribute__((aligned(16))) float h1_s[HID];
    __shared__ __attribute__((aligned(16))) float h2_s[HID];
    __shared__ __attribute__((aligned(16))) float po_s[HID];
    __shared__ __attribute__((aligned(16))) float wlds[NTHR * WPAD];  // 86 KB

    const int tid  = threadIdx.x;
    const int b    = blockIdx.x;
    const int j    = tid >> 1;   // gate row 0..383 (torch order i,f,g,o)
    const int half = tid & 1;

    // stage this batch's x sequence (I=1 -> 4 KiB)
    for (int i = tid; i < TLEN; i += NTHR) x_s[i] = x[b * TLEN + i];

    // ---- phase-A weights: Whh0[j][48*half .. +47], 12 NAMED float4s ----
    const float4* p0 = reinterpret_cast<const float4*>(Whh0 + j * HID + 48 * half);
    float4 a0 = p0[0],  a1 = p0[1],  a2 = p0[2],  a3 = p0[3];
    float4 a4 = p0[4],  a5 = p0[5],  a6 = p0[6],  a7 = p0[7];
    float4 a8 = p0[8],  a9 = p0[9],  a10 = p0[10], a11 = p0[11];

    // ---- phase-C weights: row j of (half ? Whh1 : Wih1) ----
    // cols 0..71 in 18 NAMED float4s; cols 72..95 (6 float4s) in LDS
    const float* m1 = half ? Whh1 : Wih1;
    const float4* p1 = reinterpret_cast<const float4*>(m1 + j * HID);
    float4 b0 = p1[0],  b1 = p1[1],  b2 = p1[2],  b3 = p1[3];
    float4 b4 = p1[4],  b5 = p1[5],  b6 = p1[6],  b7 = p1[7];
    float4 b8 = p1[8],  b9 = p1[9],  b10 = p1[10], b11 = p1[11];
    float4 b12 = p1[12], b13 = p1[13], b14 = p1[14], b15 = p1[15];
    float4 b16 = p1[16], b17 = p1[17];
    {
        float4* wl = reinterpret_cast<float4*>(wlds + tid * WPAD);
        wl[0] = p1[18]; wl[1] = p1[19]; wl[2] = p1[20];
        wl[3] = p1[21]; wl[4] = p1[22]; wl[5] = p1[23];
    }

    const float bias0 = bih0[j] + bhh0[j];
    const float wx0   = Wih0[j];              // W_ih0 is [384,1]
    const float bias1 = bih1[j] + bhh1[j];
    const float wl_u  = (tid < HID) ? Wl[tid] : 0.0f;
    const float bl0   = bl[0];

    float c1 = 0.0f, c2 = 0.0f;
    if (tid < HID) { h1_s[tid] = 0.0f; h2_s[tid] = 0.0f; }
    __syncthreads();

    #pragma unroll 1
    for (int t = 0; t < TLEN; ++t) {
        // ---- A: g0[j] = bias0 + x_t*Wih0[j] + dot(Whh0[j], h1_prev) ----
        {
            const float4* hA = reinterpret_cast<const float4*>(h1_s + 48 * half);
            float4 acc = make_float4(0.f, 0.f, 0.f, 0.f);
            QFMA(a0, hA, 0)  QFMA(a1, hA, 1)  QFMA(a2, hA, 2)  QFMA(a3, hA, 3)
            QFMA(a4, hA, 4)  QFMA(a5, hA, 5)  QFMA(a6, hA, 6)  QFMA(a7, hA, 7)
            QFMA(a8, hA, 8)  QFMA(a9, hA, 9)  QFMA(a10, hA, 10) QFMA(a11, hA, 11)
            float s = (acc.x + acc.y) + (acc.z + acc.w);
            s += __shfl_xor(s, 1);
            if (half == 0) g_s[j] = s + bias0 + wx0 * x_s[t];
        }
        __syncthreads();
        // ---- B: layer-1 pointwise (96 units) ----
        if (tid < HID) {
            float gi = g_s[tid];
            float gf = g_s[HID + tid];
            float gg = g_s[2 * HID + tid];
            float go = g_s[3 * HID + tid];
            c1 = sigf(gf) * c1 + sigf(gi) * tanh_fast(gg);
            h1_s[tid] = sigf(go) * tanh_fast(c1);
        }
        __syncthreads();
        // ---- C: g1[j] = bias1 + dot(Wih1[j], h1_t) + dot(Whh1[j], h2_prev) ----
        {
            const float4* hC = reinterpret_cast<const float4*>(half ? h2_s : h1_s);
            float4 acc = make_float4(0.f, 0.f, 0.f, 0.f);
            QFMA(b0, hC, 0)   QFMA(b1, hC, 1)   QFMA(b2, hC, 2)   QFMA(b3, hC, 3)
            QFMA(b4, hC, 4)   QFMA(b5, hC, 5)   QFMA(b6, hC, 6)   QFMA(b7, hC, 7)
            QFMA(b8, hC, 8)   QFMA(b9, hC, 9)   QFMA(b10, hC, 10) QFMA(b11, hC, 11)
            QFMA(b12, hC, 12) QFMA(b13, hC, 13) QFMA(b14, hC, 14) QFMA(b15, hC, 15)
            QFMA(b16, hC, 16) QFMA(b17, hC, 17)
            // tail cols 72..95 from LDS; opaque zero keeps these reads inside the
            // loop (otherwise LICM hoists 24 loop-invariant floats back into VGPRs)
            int zr;
            asm volatile("v_mov_b32 %0, 0" : "=v"(zr));
            const float4* wl = reinterpret_cast<const float4*>(wlds + tid * WPAD + zr);
            QFMA(wl[0], hC, 18) QFMA(wl[1], hC, 19) QFMA(wl[2], hC, 20)
            QFMA(wl[3], hC, 21) QFMA(wl[4], hC, 22) QFMA(wl[5], hC, 23)
            float s = (acc.x + acc.y) + (acc.z + acc.w);
            s += __shfl_xor(s, 1);
            if (half == 0) g_s[j] = s + bias1;
        }
        __syncthreads();
        // ---- D: layer-2 pointwise + linear-head partials ----
        if (tid < HID) {
            float gi = g_s[tid];
            float gf = g_s[HID + tid];
            float gg = g_s[2 * HID + tid];
            float go = g_s[3 * HID + tid];
            c2 = sigf(gf) * c2 + sigf(gi) * tanh_fast(gg);
            float h2 = sigf(go) * tanh_fast(c2);
            h2_s[tid] = h2;
            po_s[tid] = wl_u * h2;
        }
        __syncthreads();
        // ---- E: out[b][t] = sum(po) + bl (wave 0; no trailing barrier needed) ----
        if (tid < 64) {
            float v = po_s[tid] + ((tid < 32) ? po_s[64 + tid] : 0.0f);
            v += __shfl_xor(v, 32);
            v += __shfl_xor(v, 16);
            v += __shfl_xor(v, 8);
            v += __shfl_xor(v, 4);
            v += __shfl_xor(v, 2);
            v += __shfl_xor(v, 1);
            if (tid == 0) out_s[t] = v + bl0;
        }
    }
    __syncthreads();
    for (int i = tid; i < TLEN; i += NTHR) out[b * TLEN + i] = out_s[i];
}

extern "C" void kernel_launch(void* const* d_in, const int* in_sizes, int n_in,
                              void* d_out, int out_size, void* d_ws, size_t ws_size,
                              hipStream_t stream)
{
    (void)in_sizes; (void)n_in; (void)d_ws; (void)ws_size; (void)out_size;
    const float* x    = (const float*)d_in[0];
    const float* Wih0 = (const float*)d_in[1];
    const float* Whh0 = (const float*)d_in[2];
    const float* bih0 = (const float*)d_in[3];
    const float* bhh0 = (const float*)d_in[4];
    const float* Wih1 = (const float*)d_in[5];
    const float* Whh1 = (const float*)d_in[6];
    const float* bih1 = (const float*)d_in[7];
    const float* bhh1 = (const float*)d_in[8];
    const float* Wl   = (const float*)d_in[9];
    const float* bl   = (const float*)d_in[10];

    lstm2_fused<<<dim3(256), dim3(NTHR), 0, stream>>>(
        x, Wih0, Whh0, bih0, bhh0, Wih1, Whh1, bih1, bhh1, Wl, bl,
        (float*)d_out);
}

// Round 5
// 2616.846 us; speedup vs baseline: 1.2546x; 1.0277x over previous
//
#include <hip/hip_runtime.h>

#define TLEN  1024
#define HID   96
#define NGATE 384
#define NTHR  768
#define WSTR  24   // floats per thread in LDS (phase-C cols 72..95)
#define WPAD  28   // row stride in floats: 112B, 16B-aligned, (7l+k)&7 bank-perm

__device__ __forceinline__ float sigf(float x) {
    return 1.0f / (1.0f + __expf(-x));
}
__device__ __forceinline__ float tanh_fast(float x) {
    float e = __expf(2.0f * x);
    return 1.0f - 2.0f / (e + 1.0f);
}

// Defeat RAGreedy rematerialization: an asm output is NOT trivially
// rematerializable, so the allocator must keep the value resident (or do a
// real costed spill) instead of silently re-loading it from global memory
// inside the loop — which is what kept VGPR_Count pinned at 84 for 4 rounds.
#define KEEP4(V) asm volatile("" : "+v"((V).x), "+v"((V).y), "+v"((V).z), "+v"((V).w))

// FMA a float4 of weights against a float4 of h (broadcast from LDS)
#define QFMA(W, HV, I)                                   \
    {                                                    \
        float4 h4 = (HV)[I];                             \
        acc.x = fmaf((W).x, h4.x, acc.x);                \
        acc.y = fmaf((W).y, h4.y, acc.y);                \
        acc.z = fmaf((W).z, h4.z, acc.z);                \
        acc.w = fmaf((W).w, h4.w, acc.w);                \
    }

extern "C" __global__ void __launch_bounds__(NTHR)
__attribute__((amdgpu_waves_per_eu(3, 3)))
lstm2_fused(const float* __restrict__ x,
            const float* __restrict__ Wih0, const float* __restrict__ Whh0,
            const float* __restrict__ bih0, const float* __restrict__ bhh0,
            const float* __restrict__ Wih1, const float* __restrict__ Whh1,
            const float* __restrict__ bih1, const float* __restrict__ bhh1,
            const float* __restrict__ Wl,   const float* __restrict__ bl,
            float* __restrict__ out)
{
    // ~95 KB LDS: one 768-thread block per CU (physical), budget = 3 waves/EU.
    __shared__ __attribute__((aligned(16))) float x_s[TLEN];
    __shared__ __attribute__((aligned(16))) float out_s[TLEN];
    __shared__ __attribute__((aligned(16))) float g_s[NGATE];
    __shared__ __attribute__((aligned(16))) float h1_s[HID];
    __shared__ __attribute__((aligned(16))) float h2_s[HID];
    __shared__ __attribute__((aligned(16))) float po_s[HID];
    __shared__ __attribute__((aligned(16))) float wlds[NTHR * WPAD];  // 86 KB

    const int tid  = threadIdx.x;
    const int b    = blockIdx.x;
    const int j    = tid >> 1;   // gate row 0..383 (torch order i,f,g,o)
    const int half = tid & 1;

    // stage this batch's x sequence (I=1 -> 4 KiB)
    for (int i = tid; i < TLEN; i += NTHR) x_s[i] = x[b * TLEN + i];

    // ---- phase-A weights: Whh0[j][48*half .. +47], 12 laundered float4s ----
    const float4* p0 = reinterpret_cast<const float4*>(Whh0 + j * HID + 48 * half);
    float4 a0 = p0[0],  a1 = p0[1],  a2 = p0[2],  a3 = p0[3];
    float4 a4 = p0[4],  a5 = p0[5],  a6 = p0[6],  a7 = p0[7];
    float4 a8 = p0[8],  a9 = p0[9],  a10 = p0[10], a11 = p0[11];
    KEEP4(a0);  KEEP4(a1);  KEEP4(a2);  KEEP4(a3);
    KEEP4(a4);  KEEP4(a5);  KEEP4(a6);  KEEP4(a7);
    KEEP4(a8);  KEEP4(a9);  KEEP4(a10); KEEP4(a11);

    // ---- phase-C weights: row j of (half ? Whh1 : Wih1) ----
    // cols 0..71 in 18 laundered float4s; cols 72..95 (6 float4s) in LDS
    const float* m1 = half ? Whh1 : Wih1;
    const float4* p1 = reinterpret_cast<const float4*>(m1 + j * HID);
    float4 b0 = p1[0],  b1 = p1[1],  b2 = p1[2],  b3 = p1[3];
    float4 b4 = p1[4],  b5 = p1[5],  b6 = p1[6],  b7 = p1[7];
    float4 b8 = p1[8],  b9 = p1[9],  b10 = p1[10], b11 = p1[11];
    float4 b12 = p1[12], b13 = p1[13], b14 = p1[14], b15 = p1[15];
    float4 b16 = p1[16], b17 = p1[17];
    KEEP4(b0);  KEEP4(b1);  KEEP4(b2);  KEEP4(b3);
    KEEP4(b4);  KEEP4(b5);  KEEP4(b6);  KEEP4(b7);
    KEEP4(b8);  KEEP4(b9);  KEEP4(b10); KEEP4(b11);
    KEEP4(b12); KEEP4(b13); KEEP4(b14); KEEP4(b15);
    KEEP4(b16); KEEP4(b17);
    {
        float4* wl = reinterpret_cast<float4*>(wlds + tid * WPAD);
        wl[0] = p1[18]; wl[1] = p1[19]; wl[2] = p1[20];
        wl[3] = p1[21]; wl[4] = p1[22]; wl[5] = p1[23];
    }

    float bias0 = bih0[j] + bhh0[j];
    float wx0   = Wih0[j];              // W_ih0 is [384,1]
    float bias1 = bih1[j] + bhh1[j];
    float wl_u  = (tid < HID) ? Wl[tid] : 0.0f;
    float bl0   = bl[0];
    asm volatile("" : "+v"(bias0), "+v"(wx0), "+v"(bias1), "+v"(wl_u), "+v"(bl0));

    float c1 = 0.0f, c2 = 0.0f;
    if (tid < HID) { h1_s[tid] = 0.0f; h2_s[tid] = 0.0f; }
    __syncthreads();

    #pragma unroll 1
    for (int t = 0; t < TLEN; ++t) {
        // ---- A: g0[j] = bias0 + x_t*Wih0[j] + dot(Whh0[j], h1_prev) ----
        {
            const float4* hA = reinterpret_cast<const float4*>(h1_s + 48 * half);
            float4 acc = make_float4(0.f, 0.f, 0.f, 0.f);
            QFMA(a0, hA, 0)  QFMA(a1, hA, 1)  QFMA(a2, hA, 2)  QFMA(a3, hA, 3)
            QFMA(a4, hA, 4)  QFMA(a5, hA, 5)  QFMA(a6, hA, 6)  QFMA(a7, hA, 7)
            QFMA(a8, hA, 8)  QFMA(a9, hA, 9)  QFMA(a10, hA, 10) QFMA(a11, hA, 11)
            float s = (acc.x + acc.y) + (acc.z + acc.w);
            s += __shfl_xor(s, 1);
            if (half == 0) g_s[j] = s + bias0 + wx0 * x_s[t];
        }
        __syncthreads();
        // ---- B: layer-1 pointwise (96 units) ----
        if (tid < HID) {
            float gi = g_s[tid];
            float gf = g_s[HID + tid];
            float gg = g_s[2 * HID + tid];
            float go = g_s[3 * HID + tid];
            c1 = sigf(gf) * c1 + sigf(gi) * tanh_fast(gg);
            h1_s[tid] = sigf(go) * tanh_fast(c1);
        }
        __syncthreads();
        // ---- C: g1[j] = bias1 + dot(Wih1[j], h1_t) + dot(Whh1[j], h2_prev) ----
        {
            const float4* hC = reinterpret_cast<const float4*>(half ? h2_s : h1_s);
            float4 acc = make_float4(0.f, 0.f, 0.f, 0.f);
            QFMA(b0, hC, 0)   QFMA(b1, hC, 1)   QFMA(b2, hC, 2)   QFMA(b3, hC, 3)
            QFMA(b4, hC, 4)   QFMA(b5, hC, 5)   QFMA(b6, hC, 6)   QFMA(b7, hC, 7)
            QFMA(b8, hC, 8)   QFMA(b9, hC, 9)   QFMA(b10, hC, 10) QFMA(b11, hC, 11)
            QFMA(b12, hC, 12) QFMA(b13, hC, 13) QFMA(b14, hC, 14) QFMA(b15, hC, 15)
            QFMA(b16, hC, 16) QFMA(b17, hC, 17)
            // tail cols 72..95 from LDS; opaque zero keeps these reads inside the
            // loop (otherwise LICM hoists 24 loop-invariant floats into VGPRs)
            int zr;
            asm volatile("v_mov_b32 %0, 0" : "=v"(zr));
            const float4* wl = reinterpret_cast<const float4*>(wlds + tid * WPAD + zr);
            QFMA(wl[0], hC, 18) QFMA(wl[1], hC, 19) QFMA(wl[2], hC, 20)
            QFMA(wl[3], hC, 21) QFMA(wl[4], hC, 22) QFMA(wl[5], hC, 23)
            float s = (acc.x + acc.y) + (acc.z + acc.w);
            s += __shfl_xor(s, 1);
            if (half == 0) g_s[j] = s + bias1;
        }
        __syncthreads();
        // ---- D: layer-2 pointwise + linear-head partials ----
        if (tid < HID) {
            float gi = g_s[tid];
            float gf = g_s[HID + tid];
            float gg = g_s[2 * HID + tid];
            float go = g_s[3 * HID + tid];
            c2 = sigf(gf) * c2 + sigf(gi) * tanh_fast(gg);
            float h2 = sigf(go) * tanh_fast(c2);
            h2_s[tid] = h2;
            po_s[tid] = wl_u * h2;
        }
        __syncthreads();
        // ---- E: out[b][t] = sum(po) + bl (wave 0; no trailing barrier needed) ----
        if (tid < 64) {
            float v = po_s[tid] + ((tid < 32) ? po_s[64 + tid] : 0.0f);
            v += __shfl_xor(v, 32);
            v += __shfl_xor(v, 16);
            v += __shfl_xor(v, 8);
            v += __shfl_xor(v, 4);
            v += __shfl_xor(v, 2);
            v += __shfl_xor(v, 1);
            if (tid == 0) out_s[t] = v + bl0;
        }
    }
    __syncthreads();
    for (int i = tid; i < TLEN; i += NTHR) out[b * TLEN + i] = out_s[i];
}

extern "C" void kernel_launch(void* const* d_in, const int* in_sizes, int n_in,
                              void* d_out, int out_size, void* d_ws, size_t ws_size,
                              hipStream_t stream)
{
    (void)in_sizes; (void)n_in; (void)d_ws; (void)ws_size; (void)out_size;
    const float* x    = (const float*)d_in[0];
    const float* Wih0 = (const float*)d_in[1];
    const float* Whh0 = (const float*)d_in[2];
    const float* bih0 = (const float*)d_in[3];
    const float* bhh0 = (const float*)d_in[4];
    const float* Wih1 = (const float*)d_in[5];
    const float* Whh1 = (const float*)d_in[6];
    const float* bih1 = (const float*)d_in[7];
    const float* bhh1 = (const float*)d_in[8];
    const float* Wl   = (const float*)d_in[9];
    const float* bl   = (const float*)d_in[10];

    lstm2_fused<<<dim3(256), dim3(NTHR), 0, stream>>>(
        x, Wih0, Whh0, bih0, bhh0, Wih1, Whh1, bih1, bhh1, Wl, bl,
        (float*)d_out);
}